// Round 8
// baseline (288.549 us; speedup 1.0000x reference)
//
#include <hip/hip_runtime.h>
#include <hip/hip_bf16.h>

#define FIN 4096
#define FOUT 4096
#define HEADS 4
#define ROWS_PER_HEAD (FOUT / HEADS)  // 1024
#define M_DIM 4096                    // 2*2048 flattened batch*seq

typedef __attribute__((ext_vector_type(8))) short bf16x8;   // 8 bf16 = 4 VGPRs
typedef __attribute__((ext_vector_type(4))) float floatx4;  // MFMA accum

#define CAST_BLOCKS ((M_DIM * FIN) / (256 * 8))  // 8192
#define TRANS_BLOCKS 2048

// ---------------------------------------------------------------------------
// Kernel 1 (merged prep, unchanged from R12/R5-verified).
// ---------------------------------------------------------------------------
__global__ __launch_bounds__(256) void prep(
    const float* __restrict__ x,    // activations [M_DIM][FIN]
    __hip_bfloat16* __restrict__ y, // bf16 activations out
    const float* __restrict__ W,
    const float* __restrict__ cw,   // [HEADS][3][3]
    const float* __restrict__ cb,   // [HEADS]
    const float* __restrict__ sk,   // [HEADS]
    __hip_bfloat16* __restrict__ Wt) {
  if (blockIdx.x < CAST_BLOCKS) {
    int idx = blockIdx.x * 256 + threadIdx.x;  // one per 8 elements
    const float4* xv = (const float4*)x;
    float4 a = xv[idx * 2];
    float4 b = xv[idx * 2 + 1];
    __hip_bfloat16 t[8];
    t[0] = __float2bfloat16(a.x); t[1] = __float2bfloat16(a.y);
    t[2] = __float2bfloat16(a.z); t[3] = __float2bfloat16(a.w);
    t[4] = __float2bfloat16(b.x); t[5] = __float2bfloat16(b.y);
    t[6] = __float2bfloat16(b.z); t[7] = __float2bfloat16(b.w);
    *(bf16x8*)(&y[(size_t)idx * 8]) = *(bf16x8*)t;
    return;
  }

  int tg = blockIdx.x - CAST_BLOCKS;  // 0..2047
  tg = (tg & 7) * (TRANS_BLOCKS / 8) + (tg >> 3);
  const int o0 = (tg >> 1) * 4;                      // base output row
  const int fs = (tg & 1) * 2048 + threadIdx.x * 8;  // col start
  const int h = o0 >> 10;
  const int r0 = o0 & (ROWS_PER_HEAD - 1);

  float kk[3][3];
#pragma unroll
  for (int i = 0; i < 3; i++)
#pragma unroll
    for (int j = 0; j < 3; j++) kk[i][j] = cw[h * 9 + i * 3 + j];
  float sig = 1.0f / (1.0f + __expf(-sk[h]));
  float bias = cb[h];

  float w[6][10];
#pragma unroll
  for (int i = 0; i < 6; i++) {
    int rr = r0 - 1 + i;
    if (rr < 0 || rr >= ROWS_PER_HEAD) {
#pragma unroll
      for (int c = 0; c < 10; c++) w[i][c] = 0.0f;
    } else {
      const float* rp = W + ((size_t)(h * ROWS_PER_HEAD + rr)) * FIN + fs;
      float4 v0 = *(const float4*)rp;
      float4 v1 = *(const float4*)(rp + 4);
      w[i][1] = v0.x; w[i][2] = v0.y; w[i][3] = v0.z; w[i][4] = v0.w;
      w[i][5] = v1.x; w[i][6] = v1.y; w[i][7] = v1.z; w[i][8] = v1.w;
      w[i][0] = (fs > 0) ? rp[-1] : 0.0f;
      w[i][9] = (fs + 8 < FIN) ? rp[8] : 0.0f;
    }
  }

#pragma unroll
  for (int j = 0; j < 4; j++) {
    float acc[8];
#pragma unroll
    for (int c = 0; c < 8; c++) acc[c] = bias + sig * w[j + 1][c + 1];
#pragma unroll
    for (int dr = 0; dr < 3; dr++) {
#pragma unroll
      for (int c = 0; c < 8; c++)
        acc[c] += kk[dr][0] * w[j + dr][c] + kk[dr][1] * w[j + dr][c + 1] +
                  kk[dr][2] * w[j + dr][c + 2];
    }
    __hip_bfloat16 t[8];
#pragma unroll
    for (int c = 0; c < 8; c++) t[c] = __float2bfloat16(acc[c]);
    *(bf16x8*)(&Wt[(size_t)(o0 + j) * FIN + fs]) = *(bf16x8*)t;
  }
}

// ---------------------------------------------------------------------------
// Kernel 2: C[m][n] = sum_k A[m][k] * B[n][k]  (NT GEMM, bf16 in, FP32 out)
// R15 = R12 ring (verified 119.4 us best) + ONE audited move: ALL FOUR
// next-tile half stages issue at the TILE TOP instead of spread at S_D/C5.
// Liveness: nbuf's A-h0/h1, B-h0/h1 are never read during tile T (last
// readers in T-1, sealed by T-1's end barrier) -> staging them anywhere in
// T is safe. gload_lds counts vmcnt only, so the ring's counted-lgkm
// structure is untouched. Effect: WAITVM(0) at tile end now covers loads
// issued ~4400 cyc earlier (vs ~300 cyc for R12's post-C5 B stages) ->
// exposed DMA drain ~0. R14's nontemporal C stores REVERTED (FETCH
// unchanged = pollution theory refuted; WRITE rose 69->88 MB, gemm +5 us).
// ---------------------------------------------------------------------------
__device__ static inline void gload_lds16(const void* g, void* l) {
  __builtin_amdgcn_global_load_lds(
      (const __attribute__((address_space(1))) void*)g,
      (__attribute__((address_space(3))) void*)l, 16, 0, 0);
}

#define BK 64
#define NT (FIN / BK)  // 64 K-tiles

__global__ __launch_bounds__(512, 2) void gemm_nt(
    const __hip_bfloat16* __restrict__ A,  // [M][K]
    const __hip_bfloat16* __restrict__ B,  // [N][K]  (= W_i, row-major)
    float* __restrict__ C,                 // [M][N] fp32
    int M, int N, int K) {
  // 8 distinct LDS objects (precise DMA alias info): 16 KB each, 128 KB.
  __shared__ __hip_bfloat16 As0h0[128 * BK];
  __shared__ __hip_bfloat16 As0h1[128 * BK];
  __shared__ __hip_bfloat16 As1h0[128 * BK];
  __shared__ __hip_bfloat16 As1h1[128 * BK];
  __shared__ __hip_bfloat16 Bs0h0[128 * BK];
  __shared__ __hip_bfloat16 Bs0h1[128 * BK];
  __shared__ __hip_bfloat16 Bs1h0[128 * BK];
  __shared__ __hip_bfloat16 Bs1h1[128 * BK];

  const int tid = threadIdx.x;
  const int lane = tid & 63;
  const int wave = tid >> 6;   // 0..7
  const int wr = wave >> 2;    // 0..1  (WARPS_M = 2)
  const int wn = wave & 3;     // 0..3  (WARPS_N = 4)
  const int fr = lane & 15;    // fragment row
  const int quad = lane >> 4;  // k-chunk selector
  const int sel = fr & 7;      // swizzle selector

  // XCD-chunked bijective swizzle (256 wgs % 8 == 0): 32 consecutive tiles
  // per XCD (mechanism confirmed in R9: HBM BW 1490->990 GB/s, same FETCH).
  const int orig = blockIdx.y * gridDim.x + blockIdx.x;
  const int swz = (orig & 7) * 32 + (orig >> 3);
  const int tile_m = (swz >> 4) * 256;
  const int tile_n = (swz & 15) * 256;

  const __hip_bfloat16* At = A + (size_t)tile_m * K;  // SGPR base
  const __hip_bfloat16* Bt = B + (size_t)tile_n * K;

  // Staging invariants: chunk position p = c*512+tid; row=p>>3, slot=p&7
  // holds global chunk g = slot^(row&7)  (proven conflict-free swizzle).
  int soff[2], doff[2];
#pragma unroll
  for (int c = 0; c < 2; c++) {
    int p = c * 512 + tid;
    int row = p >> 3;
    int g = (p & 7) ^ (row & 7);
    soff[c] = row * K + g * 8;  // elems
    doff[c] = p * 8;            // elems into half-buffer
  }
  // Fragment read invariants (all local rows == fr mod 8 -> sel works).
  int aro[4], bro[2], co[2];
#pragma unroll
  for (int u = 0; u < 4; u++) aro[u] = (wr * 16 + u * 32 + fr) * 64;
#pragma unroll
  for (int j = 0; j < 2; j++) bro[j] = (wn * 16 + j * 64 + fr) * 64;
#pragma unroll
  for (int kk = 0; kk < 2; kk++) co[kk] = ((kk * 4 + quad) ^ sel) * 8;

  floatx4 acc[8][4];
#pragma unroll
  for (int i = 0; i < 8; i++)
#pragma unroll
    for (int j = 0; j < 4; j++) acc[i][j] = (floatx4){0.f, 0.f, 0.f, 0.f};

  // Fragment ring: afr[mslot][u] (A m-half, current k-half);
  // bfr[kslot][nh][j] (B both n-halves, per k-half slot).
  bf16x8 afr[2][4];
  bf16x8 bfr[2][2][2];

#define STAGE(GBASE, DST, TILE, HALF)                                    \
  do {                                                                   \
    const __hip_bfloat16* _s =                                           \
        GBASE + (size_t)(HALF) * 128 * K + (size_t)(TILE) * BK;          \
    _Pragma("unroll") for (int _c = 0; _c < 2; _c++) {                   \
      gload_lds16(_s + soff[_c], DST + doff[_c]);                        \
    }                                                                    \
  } while (0)

#define LOADA4(MS, SRC, KK)                                              \
  do {                                                                   \
    _Pragma("unroll") for (int _u = 0; _u < 4; _u++) {                   \
      afr[MS][_u] = *(const bf16x8*)&SRC[aro[_u] + co[KK]];              \
    }                                                                    \
  } while (0)

#define LOADB2(KS, NH, SRC, KK)                                          \
  do {                                                                   \
    _Pragma("unroll") for (int _j = 0; _j < 2; _j++) {                   \
      bfr[KS][NH][_j] = *(const bf16x8*)&SRC[bro[_j] + co[KK]];          \
    }                                                                    \
  } while (0)

#define MMA8(MS, KS, NH)                                                 \
  do {                                                                   \
    __builtin_amdgcn_s_setprio(1);                                       \
    _Pragma("unroll") for (int _u = 0; _u < 4; _u++) {                   \
      _Pragma("unroll") for (int _j = 0; _j < 2; _j++) {                 \
        acc[(MS) * 4 + _u][(NH) * 2 + _j] =                              \
            __builtin_amdgcn_mfma_f32_16x16x32_bf16(                     \
                afr[MS][_u], bfr[KS][NH][_j],                            \
                acc[(MS) * 4 + _u][(NH) * 2 + _j], 0, 0, 0);             \
      }                                                                  \
    }                                                                    \
    __builtin_amdgcn_s_setprio(0);                                       \
  } while (0)

#define BAR() __builtin_amdgcn_s_barrier()
#define WAITVM(N) asm volatile("s_waitcnt vmcnt(" #N ")" ::: "memory")
#define FENCE_LGKM(N)                                                    \
  do {                                                                   \
    __builtin_amdgcn_sched_barrier(0);                                   \
    asm volatile("s_waitcnt lgkmcnt(" #N ")" ::: "memory");              \
    __builtin_amdgcn_sched_barrier(0);                                   \
  } while (0)

  // One K-tile. Clusters C1..C7 here; C8 = MMA8(1,1,0) deferred past the
  // barrier. ALL 8 next-tile stage loads issue at TILE TOP (nbuf halves are
  // dead all tile; gload_lds affects vmcnt only). Read segments unchanged:
  // S_A(8) C1 [S_B] C2 [S_C S_D] lgkm(8) C3 C4 [S_E] lgkm(4) C5 C6 lgkm(0)
  // C7 [vmcnt(0)] BAR. Waits audited as in R12 (DS in-order retirement).
#define TBODY(T, CA0, CA1, CB0, CB1, NA0, NA1, NB0, NB1, DO_C8, DO_STAGE) \
  do {                                                                    \
    if (DO_STAGE) {                                                       \
      STAGE(At, NA0, (T) + 1, 0);                                         \
      STAGE(At, NA1, (T) + 1, 1);                                         \
      STAGE(Bt, NB0, (T) + 1, 0);                                         \
      STAGE(Bt, NB1, (T) + 1, 1);                                         \
    }                                                                     \
    LOADA4(0, CA0, 0); /* S_A */                                          \
    LOADB2(0, 0, CB0, 0);                                                 \
    LOADB2(0, 1, CB1, 0);                                                 \
    if (DO_C8) MMA8(1, 1, 0); /* prev tile's C8 */                        \
    FENCE_LGKM(0);                                                        \
    MMA8(0, 0, 0); /* C1 */                                               \
    LOADA4(1, CA1, 0); /* S_B */                                          \
    MMA8(0, 0, 1); /* C2 */                                               \
    LOADB2(1, 0, CB0, 1); /* S_C */                                       \
    LOADB2(1, 1, CB1, 1);                                                 \
    LOADA4(0, CA0, 1); /* S_D */                                          \
    FENCE_LGKM(8);                                                        \
    MMA8(1, 0, 1); /* C3 */                                               \
    MMA8(1, 0, 0); /* C4 */                                               \
    LOADA4(1, CA1, 1); /* S_E */                                          \
    FENCE_LGKM(4);                                                        \
    MMA8(0, 1, 0); /* C5 */                                               \
    MMA8(0, 1, 1); /* C6 */                                               \
    FENCE_LGKM(0);                                                        \
    MMA8(1, 1, 1); /* C7 */                                               \
    if (DO_STAGE) WAITVM(0);                                              \
    BAR();                                                                \
  } while (0)

  // ---- Prologue: stage tile0 fully into buf0.
  STAGE(At, As0h0, 0, 0);
  STAGE(At, As0h1, 0, 1);
  STAGE(Bt, Bs0h0, 0, 0);
  STAGE(Bt, Bs0h1, 0, 1);
  WAITVM(0);
  BAR();

  // ---- Tile 0 (buf0, no deferred C8 yet).
  TBODY(0, As0h0, As0h1, Bs0h0, Bs0h1, As1h0, As1h1, Bs1h0, Bs1h1, 0, 1);

  // ---- Tiles 1..62 as explicit (odd, even) pairs; compile-time buffers.
#pragma unroll 1
  for (int t = 1; t < NT - 1; t += 2) {
    TBODY(t, As1h0, As1h1, Bs1h0, Bs1h1, As0h0, As0h1, Bs0h0, Bs0h1, 1, 1);
    TBODY(t + 1, As0h0, As0h1, Bs0h0, Bs0h1, As1h0, As1h1, Bs1h0, Bs1h1, 1, 1);
  }

  // ---- Tile 63 (buf1): no staging, then the final deferred C8.
  TBODY(NT - 1, As1h0, As1h1, Bs1h0, Bs1h1, As0h0, As0h1, Bs0h0, Bs0h1, 1, 0);
  MMA8(1, 1, 0);  // tile 63's C8

#undef TBODY
#undef FENCE_LGKM
#undef STAGE
#undef LOADA4
#undef LOADB2
#undef MMA8
#undef BAR
#undef WAITVM

  // ---- Epilogue: C/D layout col = lane&15, row = quad*4 + reg. Plain
  // stores (nt reverted: raised WRITE 69->88 MB, FETCH unchanged).
#pragma unroll
  for (int i = 0; i < 8; i++) {
    int mb = tile_m + wr * 16 + i * 32 + quad * 4;
#pragma unroll
    for (int j = 0; j < 4; j++) {
      int n = tile_n + wn * 16 + j * 64 + fr;
#pragma unroll
      for (int r = 0; r < 4; r++) {
        C[(size_t)(mb + r) * N + n] = acc[i][j][r];
      }
    }
  }
}

// ---------------------------------------------------------------------------
extern "C" void kernel_launch(void* const* d_in, const int* in_sizes, int n_in,
                              void* d_out, int out_size, void* d_ws,
                              size_t ws_size, hipStream_t stream) {
  const float* inp = (const float*)d_in[0];     // [2,2048,4096] fp32
  const float* W = (const float*)d_in[1];       // [4096,4096] fp32
  const float* conv_w = (const float*)d_in[2];  // [4,1,3,3] fp32
  const float* conv_b = (const float*)d_in[3];  // [4] fp32
  const float* sk_wt = (const float*)d_in[4];   // [4,1,1] fp32
  float* out = (float*)d_out;                   // [2,2048,4096] fp32

  __hip_bfloat16* Wt = (__hip_bfloat16*)d_ws;   // 32 MB
  __hip_bfloat16* Ab =
      (__hip_bfloat16*)((char*)d_ws + (size_t)(32u << 20));  // next 32 MB

  // 1) merged prep: cast activations + transform weight, one launch
  prep<<<CAST_BLOCKS + TRANS_BLOCKS, 256, 0, stream>>>(inp, Ab, W, conv_w,
                                                       conv_b, sk_wt, Wt);
  // 2) out[m][n] = sum_k Ab[m][k] * Wt[n][k]  (256x256 tiles, ring schedule,
  //    all-at-top staging)
  dim3 grid(FOUT / 256, M_DIM / 256);
  gemm_nt<<<grid, 512, 0, stream>>>(Ab, Wt, out, M_DIM, FOUT, FIN);
}

// Round 10
// 283.363 us; speedup vs baseline: 1.0183x; 1.0183x over previous
//
#include <hip/hip_runtime.h>
#include <hip/hip_bf16.h>

#define FIN 4096
#define FOUT 4096
#define HEADS 4
#define ROWS_PER_HEAD (FOUT / HEADS)  // 1024
#define M_DIM 4096                    // 2*2048 flattened batch*seq

typedef __attribute__((ext_vector_type(8))) short bf16x8;   // 8 bf16 = 4 VGPRs
typedef __attribute__((ext_vector_type(4))) float floatx4;  // MFMA accum

#define CAST_BLOCKS ((M_DIM * FIN) / (256 * 8))  // 8192
#define TRANS_BLOCKS 2048

// ---------------------------------------------------------------------------
// Kernel 1 (merged prep, R12-exact / best-verified).
// ---------------------------------------------------------------------------
__global__ __launch_bounds__(256) void prep(
    const float* __restrict__ x,    // activations [M_DIM][FIN]
    __hip_bfloat16* __restrict__ y, // bf16 activations out
    const float* __restrict__ W,
    const float* __restrict__ cw,   // [HEADS][3][3]
    const float* __restrict__ cb,   // [HEADS]
    const float* __restrict__ sk,   // [HEADS]
    __hip_bfloat16* __restrict__ Wt) {
  if (blockIdx.x < CAST_BLOCKS) {
    int idx = blockIdx.x * 256 + threadIdx.x;  // one per 8 elements
    const float4* xv = (const float4*)x;
    float4 a = xv[idx * 2];
    float4 b = xv[idx * 2 + 1];
    __hip_bfloat16 t[8];
    t[0] = __float2bfloat16(a.x); t[1] = __float2bfloat16(a.y);
    t[2] = __float2bfloat16(a.z); t[3] = __float2bfloat16(a.w);
    t[4] = __float2bfloat16(b.x); t[5] = __float2bfloat16(b.y);
    t[6] = __float2bfloat16(b.z); t[7] = __float2bfloat16(b.w);
    *(bf16x8*)(&y[(size_t)idx * 8]) = *(bf16x8*)t;
    return;
  }

  int tg = blockIdx.x - CAST_BLOCKS;  // 0..2047
  tg = (tg & 7) * (TRANS_BLOCKS / 8) + (tg >> 3);
  const int o0 = (tg >> 1) * 4;                      // base output row
  const int fs = (tg & 1) * 2048 + threadIdx.x * 8;  // col start
  const int h = o0 >> 10;
  const int r0 = o0 & (ROWS_PER_HEAD - 1);

  float kk[3][3];
#pragma unroll
  for (int i = 0; i < 3; i++)
#pragma unroll
    for (int j = 0; j < 3; j++) kk[i][j] = cw[h * 9 + i * 3 + j];
  float sig = 1.0f / (1.0f + __expf(-sk[h]));
  float bias = cb[h];

  float w[6][10];
#pragma unroll
  for (int i = 0; i < 6; i++) {
    int rr = r0 - 1 + i;
    if (rr < 0 || rr >= ROWS_PER_HEAD) {
#pragma unroll
      for (int c = 0; c < 10; c++) w[i][c] = 0.0f;
    } else {
      const float* rp = W + ((size_t)(h * ROWS_PER_HEAD + rr)) * FIN + fs;
      float4 v0 = *(const float4*)rp;
      float4 v1 = *(const float4*)(rp + 4);
      w[i][1] = v0.x; w[i][2] = v0.y; w[i][3] = v0.z; w[i][4] = v0.w;
      w[i][5] = v1.x; w[i][6] = v1.y; w[i][7] = v1.z; w[i][8] = v1.w;
      w[i][0] = (fs > 0) ? rp[-1] : 0.0f;
      w[i][9] = (fs + 8 < FIN) ? rp[8] : 0.0f;
    }
  }

#pragma unroll
  for (int j = 0; j < 4; j++) {
    float acc[8];
#pragma unroll
    for (int c = 0; c < 8; c++) acc[c] = bias + sig * w[j + 1][c + 1];
#pragma unroll
    for (int dr = 0; dr < 3; dr++) {
#pragma unroll
      for (int c = 0; c < 8; c++)
        acc[c] += kk[dr][0] * w[j + dr][c] + kk[dr][1] * w[j + dr][c + 1] +
                  kk[dr][2] * w[j + dr][c + 2];
    }
    __hip_bfloat16 t[8];
#pragma unroll
    for (int c = 0; c < 8; c++) t[c] = __float2bfloat16(acc[c]);
    *(bf16x8*)(&Wt[(size_t)(o0 + j) * FIN + fs]) = *(bf16x8*)t;
  }
}

// ---------------------------------------------------------------------------
// Kernel 2: C[m][n] = sum_k A[m][k] * B[n][k]  (NT GEMM, bf16 in, FP32 out)
// R17 = R12 ring EXACT (best verified: gemm 119.4-122 us, total 283.3).
// Ring: 8 clusters of 8 MFMA per K-tile, fragments ds_read 2-2.5 clusters
// ahead into audited-dead register slots, counted lgkm waits (0/8/4/0),
// ONE barrier per tile, C8 deferred past the barrier, stages spread mid-tile
// (S_D-slot + post-C5 -- placement verified optimal: top-staging -14 us,
// BAR_MID restage -9 us, nt-store -5 us, all reverted).
// Session plateau analysis: LDS-read pipe (~2560 cyc/tile/CU) vs MFMA pipe
// (2480 cyc) are balanced; ~50% MfmaUtil = partial overlap attractor across
// ALL schedule families tried (2-phase, 8-phase x2, ring x4, 4 blocks/CU).
// ---------------------------------------------------------------------------
__device__ static inline void gload_lds16(const void* g, void* l) {
  __builtin_amdgcn_global_load_lds(
      (const __attribute__((address_space(1))) void*)g,
      (__attribute__((address_space(3))) void*)l, 16, 0, 0);
}

#define BK 64
#define NT (FIN / BK)  // 64 K-tiles

__global__ __launch_bounds__(512, 2) void gemm_nt(
    const __hip_bfloat16* __restrict__ A,  // [M][K]
    const __hip_bfloat16* __restrict__ B,  // [N][K]  (= W_i, row-major)
    float* __restrict__ C,                 // [M][N] fp32
    int M, int N, int K) {
  // 8 distinct LDS objects (precise DMA alias info): 16 KB each, 128 KB.
  __shared__ __hip_bfloat16 As0h0[128 * BK];
  __shared__ __hip_bfloat16 As0h1[128 * BK];
  __shared__ __hip_bfloat16 As1h0[128 * BK];
  __shared__ __hip_bfloat16 As1h1[128 * BK];
  __shared__ __hip_bfloat16 Bs0h0[128 * BK];
  __shared__ __hip_bfloat16 Bs0h1[128 * BK];
  __shared__ __hip_bfloat16 Bs1h0[128 * BK];
  __shared__ __hip_bfloat16 Bs1h1[128 * BK];

  const int tid = threadIdx.x;
  const int lane = tid & 63;
  const int wave = tid >> 6;   // 0..7
  const int wr = wave >> 2;    // 0..1  (WARPS_M = 2)
  const int wn = wave & 3;     // 0..3  (WARPS_N = 4)
  const int fr = lane & 15;    // fragment row
  const int quad = lane >> 4;  // k-chunk selector
  const int sel = fr & 7;      // swizzle selector

  // XCD-chunked bijective swizzle (256 wgs % 8 == 0): 32 consecutive tiles
  // per XCD (mechanism confirmed in R9: HBM BW 1490->990 GB/s, same FETCH).
  const int orig = blockIdx.y * gridDim.x + blockIdx.x;
  const int swz = (orig & 7) * 32 + (orig >> 3);
  const int tile_m = (swz >> 4) * 256;
  const int tile_n = (swz & 15) * 256;

  const __hip_bfloat16* At = A + (size_t)tile_m * K;  // SGPR base
  const __hip_bfloat16* Bt = B + (size_t)tile_n * K;

  // Staging invariants: chunk position p = c*512+tid; row=p>>3, slot=p&7
  // holds global chunk g = slot^(row&7)  (proven conflict-free swizzle).
  int soff[2], doff[2];
#pragma unroll
  for (int c = 0; c < 2; c++) {
    int p = c * 512 + tid;
    int row = p >> 3;
    int g = (p & 7) ^ (row & 7);
    soff[c] = row * K + g * 8;  // elems
    doff[c] = p * 8;            // elems into half-buffer
  }
  // Fragment read invariants (all local rows == fr mod 8 -> sel works).
  int aro[4], bro[2], co[2];
#pragma unroll
  for (int u = 0; u < 4; u++) aro[u] = (wr * 16 + u * 32 + fr) * 64;
#pragma unroll
  for (int j = 0; j < 2; j++) bro[j] = (wn * 16 + j * 64 + fr) * 64;
#pragma unroll
  for (int kk = 0; kk < 2; kk++) co[kk] = ((kk * 4 + quad) ^ sel) * 8;

  floatx4 acc[8][4];
#pragma unroll
  for (int i = 0; i < 8; i++)
#pragma unroll
    for (int j = 0; j < 4; j++) acc[i][j] = (floatx4){0.f, 0.f, 0.f, 0.f};

  // Fragment ring: afr[mslot][u] (A m-half, current k-half);
  // bfr[kslot][nh][j] (B both n-halves, per k-half slot).
  bf16x8 afr[2][4];
  bf16x8 bfr[2][2][2];

#define STAGE(GBASE, DST, TILE, HALF)                                    \
  do {                                                                   \
    const __hip_bfloat16* _s =                                           \
        GBASE + (size_t)(HALF) * 128 * K + (size_t)(TILE) * BK;          \
    _Pragma("unroll") for (int _c = 0; _c < 2; _c++) {                   \
      gload_lds16(_s + soff[_c], DST + doff[_c]);                        \
    }                                                                    \
  } while (0)

#define LOADA4(MS, SRC, KK)                                              \
  do {                                                                   \
    _Pragma("unroll") for (int _u = 0; _u < 4; _u++) {                   \
      afr[MS][_u] = *(const bf16x8*)&SRC[aro[_u] + co[KK]];              \
    }                                                                    \
  } while (0)

#define LOADB2(KS, NH, SRC, KK)                                          \
  do {                                                                   \
    _Pragma("unroll") for (int _j = 0; _j < 2; _j++) {                   \
      bfr[KS][NH][_j] = *(const bf16x8*)&SRC[bro[_j] + co[KK]];          \
    }                                                                    \
  } while (0)

#define MMA8(MS, KS, NH)                                                 \
  do {                                                                   \
    __builtin_amdgcn_s_setprio(1);                                       \
    _Pragma("unroll") for (int _u = 0; _u < 4; _u++) {                   \
      _Pragma("unroll") for (int _j = 0; _j < 2; _j++) {                 \
        acc[(MS) * 4 + _u][(NH) * 2 + _j] =                              \
            __builtin_amdgcn_mfma_f32_16x16x32_bf16(                     \
                afr[MS][_u], bfr[KS][NH][_j],                            \
                acc[(MS) * 4 + _u][(NH) * 2 + _j], 0, 0, 0);             \
      }                                                                  \
    }                                                                    \
    __builtin_amdgcn_s_setprio(0);                                       \
  } while (0)

#define BAR() __builtin_amdgcn_s_barrier()
#define WAITVM(N) asm volatile("s_waitcnt vmcnt(" #N ")" ::: "memory")
#define FENCE_LGKM(N)                                                    \
  do {                                                                   \
    __builtin_amdgcn_sched_barrier(0);                                   \
    asm volatile("s_waitcnt lgkmcnt(" #N ")" ::: "memory");              \
    __builtin_amdgcn_sched_barrier(0);                                   \
  } while (0)

  // One K-tile. Clusters C1..C7 here; C8 = MMA8(1,1,0) deferred past the
  // barrier (runs at the top of the NEXT tile body, hiding the read bubble).
  // Read segments: S_A(8: afr0 m0k0 + bfr0 k0) | S_B(4: afr1 m1k0) |
  // S_C(4: bfr1 k1) | S_D(4: afr0 m0k1) | S_E(4: afr1 m1k1).
  // Issue: [S_A] C1 [S_B] C2 [S_C S_D stagesA] C3 [] C4 [S_E] C5 [stagesB]
  // C6 [] C7. Waits: C1 lgkm(0); C3 needs S_B, outstanding 12 -> lgkm(8);
  // C5 needs S_C+S_D, outstanding 12 -> lgkm(4); C7 needs S_E -> lgkm(0).
  // Slot WAR (in-order issue guards): afr[0] m0k0 dies@C2 < S_D issue;
  // afr[1] m1k0 dies@C4 < S_E issue; bfr[1] prev-k1 dies@C8(top) < S_C;
  // bfr[0] prev-k0 dies@prev C4 < S_A. Stages -> buffers whose last reader
  // passed >=1 barrier ago; WAITVM(0) before the tile barrier when staging.
#define TBODY(T, CA0, CA1, CB0, CB1, NA0, NA1, NB0, NB1, DO_C8, DO_STAGE) \
  do {                                                                    \
    LOADA4(0, CA0, 0);                                                    \
    LOADB2(0, 0, CB0, 0);                                                 \
    LOADB2(0, 1, CB1, 0);                                                 \
    if (DO_C8) MMA8(1, 1, 0); /* prev tile's C8 */                        \
    FENCE_LGKM(0);                                                        \
    MMA8(0, 0, 0); /* C1 */                                               \
    LOADA4(1, CA1, 0); /* S_B */                                          \
    MMA8(0, 0, 1); /* C2 */                                               \
    LOADB2(1, 0, CB0, 1); /* S_C */                                       \
    LOADB2(1, 1, CB1, 1);                                                 \
    LOADA4(0, CA0, 1); /* S_D (dead slot; deepened read-ahead) */         \
    if (DO_STAGE) {                                                       \
      STAGE(At, NA0, (T) + 1, 0);                                         \
      STAGE(At, NA1, (T) + 1, 1);                                         \
    }                                                                     \
    FENCE_LGKM(8);                                                        \
    MMA8(1, 0, 1); /* C3 */                                               \
    MMA8(1, 0, 0); /* C4 */                                               \
    LOADA4(1, CA1, 1); /* S_E */                                          \
    FENCE_LGKM(4);                                                        \
    MMA8(0, 1, 0); /* C5 */                                               \
    if (DO_STAGE) {                                                       \
      STAGE(Bt, NB0, (T) + 1, 0);                                         \
      STAGE(Bt, NB1, (T) + 1, 1);                                         \
    }                                                                     \
    MMA8(0, 1, 1); /* C6 */                                               \
    FENCE_LGKM(0);                                                        \
    MMA8(1, 1, 1); /* C7 */                                               \
    if (DO_STAGE) WAITVM(0);                                              \
    BAR();                                                                \
  } while (0)

  // ---- Prologue: stage tile0 fully into buf0.
  STAGE(At, As0h0, 0, 0);
  STAGE(At, As0h1, 0, 1);
  STAGE(Bt, Bs0h0, 0, 0);
  STAGE(Bt, Bs0h1, 0, 1);
  WAITVM(0);
  BAR();

  // ---- Tile 0 (buf0, no deferred C8 yet).
  TBODY(0, As0h0, As0h1, Bs0h0, Bs0h1, As1h0, As1h1, Bs1h0, Bs1h1, 0, 1);

  // ---- Tiles 1..62 as explicit (odd, even) pairs; compile-time buffers.
#pragma unroll 1
  for (int t = 1; t < NT - 1; t += 2) {
    TBODY(t, As1h0, As1h1, Bs1h0, Bs1h1, As0h0, As0h1, Bs0h0, Bs0h1, 1, 1);
    TBODY(t + 1, As0h0, As0h1, Bs0h0, Bs0h1, As1h0, As1h1, Bs1h0, Bs1h1, 1, 1);
  }

  // ---- Tile 63 (buf1): no staging, then the final deferred C8.
  TBODY(NT - 1, As1h0, As1h1, Bs1h0, Bs1h1, As0h0, As0h1, Bs0h0, Bs0h1, 1, 0);
  MMA8(1, 1, 0);  // tile 63's C8

#undef TBODY
#undef FENCE_LGKM
#undef STAGE
#undef LOADA4
#undef LOADB2
#undef MMA8
#undef BAR
#undef WAITVM

  // ---- Epilogue: C/D layout col = lane&15, row = quad*4 + reg.
#pragma unroll
  for (int i = 0; i < 8; i++) {
    int mb = tile_m + wr * 16 + i * 32 + quad * 4;
#pragma unroll
    for (int j = 0; j < 4; j++) {
      int n = tile_n + wn * 16 + j * 64 + fr;
#pragma unroll
      for (int r = 0; r < 4; r++) {
        C[(size_t)(mb + r) * N + n] = acc[i][j][r];
      }
    }
  }
}

// ---------------------------------------------------------------------------
extern "C" void kernel_launch(void* const* d_in, const int* in_sizes, int n_in,
                              void* d_out, int out_size, void* d_ws,
                              size_t ws_size, hipStream_t stream) {
  const float* inp = (const float*)d_in[0];     // [2,2048,4096] fp32
  const float* W = (const float*)d_in[1];       // [4096,4096] fp32
  const float* conv_w = (const float*)d_in[2];  // [4,1,3,3] fp32
  const float* conv_b = (const float*)d_in[3];  // [4] fp32
  const float* sk_wt = (const float*)d_in[4];   // [4,1,1] fp32
  float* out = (float*)d_out;                   // [2,2048,4096] fp32

  __hip_bfloat16* Wt = (__hip_bfloat16*)d_ws;   // 32 MB
  __hip_bfloat16* Ab =
      (__hip_bfloat16*)((char*)d_ws + (size_t)(32u << 20));  // next 32 MB

  // 1) merged prep: cast activations + transform weight, one launch
  prep<<<CAST_BLOCKS + TRANS_BLOCKS, 256, 0, stream>>>(inp, Ab, W, conv_w,
                                                       conv_b, sk_wt, Wt);
  // 2) out[m][n] = sum_k Ab[m][k] * Wt[n][k]  (256x256 tiles, ring schedule)
  dim3 grid(FOUT / 256, M_DIM / 256);
  gemm_nt<<<grid, 512, 0, stream>>>(Ab, Wt, out, M_DIM, FOUT, FIN);
}